// Round 11
// baseline (49.527 us; speedup 1.0000x reference)
//
#include <hip/hip_runtime.h>
#include <math.h>

namespace {

constexpr int L      = 3750;
constexpr int NPAIR  = L / 2;     // 1875 float2 per row
constexpr int BLK    = 256;
constexpr int ROWS   = 2;         // rows per block
constexpr int CH     = 15;        // chunk per thread (odd stride => conflict-free)
constexpr int NCHUNK = L / CH;    // 250 active chunk threads
constexpr int NFULL  = NPAIR / BLK;          // 7 full I/O rounds
constexpr int NTAIL  = NPAIR - NFULL * BLK;  // 83
constexpr float EPS  = 1e-5f;

__device__ __forceinline__ float frcp(float x)  { return __builtin_amdgcn_rcpf(x); }
__device__ __forceinline__ float fsqrt(float x) { return __builtin_amdgcn_sqrtf(x); }
__device__ __forceinline__ float frsq(float x)  { return __builtin_amdgcn_rsqf(x); }

__global__ __launch_bounds__(BLK, 5)
void preproc_kernel(const float* __restrict__ in, float* __restrict__ out) {
    // per-row LDS array, reused: staging -> y-prefix -> u^2-prefix -> result
    __shared__ __align__(16) float sp[ROWS][L + 2];
    __shared__ float sred[ROWS][8];   // wave partials: [0:4) sum, [4:8) sumsq

    const int tid  = threadIdx.x;
    const int lane = tid & 63;
    const int wave = tid >> 6;
    const size_t row0 = (size_t)blockIdx.x * (size_t)ROWS;

    const bool active = (tid < NCHUNK);
    const int  base   = tid * CH;
    const bool tl     = (tid < NTAIL);

    // ---- 1. coalesced load both rows (all loads in flight, then LDS writes) ----
    {
        float2 v[ROWS][NFULL + 1];
        #pragma unroll
        for (int r = 0; r < ROWS; ++r) {
            const float2* rin2 = reinterpret_cast<const float2*>(in + (row0 + r) * L);
            #pragma unroll
            for (int k = 0; k < NFULL; ++k) v[r][k] = rin2[k * BLK + tid];
            if (tl) v[r][NFULL] = rin2[NFULL * BLK + tid];
        }
        #pragma unroll
        for (int r = 0; r < ROWS; ++r) {
            float2* sp2 = reinterpret_cast<float2*>(&sp[r][0]);
            #pragma unroll
            for (int k = 0; k < NFULL; ++k) sp2[k * BLK + tid] = v[r][k];
            if (tl) sp2[NFULL * BLK + tid] = v[r][NFULL];
        }
    }
    __syncthreads();                          // B1

    // ---- 2. chunk -> registers; block reduce per row ----
    float y[ROWS][CH];
    float cy[ROWS], iy[ROWS];
    #pragma unroll
    for (int r = 0; r < ROWS; ++r) {
        float c = 0.f, c2 = 0.f;
        if (active) {
            #pragma unroll
            for (int j = 0; j < CH; ++j) {
                const float v = sp[r][base + j];
                y[r][j] = v;
                c  += v;
                c2  = fmaf(v, v, c2);
            }
        } else {
            #pragma unroll
            for (int j = 0; j < CH; ++j) y[r][j] = 0.f;
        }
        float i1 = c;
        #pragma unroll
        for (int d = 1; d < 64; d <<= 1) {
            const float u = __shfl_up(i1, (unsigned)d, 64);
            if (lane >= d) i1 += u;
        }
        float t2 = c2;
        #pragma unroll
        for (int d = 1; d < 64; d <<= 1) t2 += __shfl_xor(t2, d, 64);
        if (lane == 63) { sred[r][wave] = i1; sred[r][4 + wave] = t2; }
        cy[r] = c; iy[r] = i1;
    }
    __syncthreads();                          // B2: sred ready, sp reads done

    float mean[ROWS], epsS[ROWS], woff[ROWS];
    #pragma unroll
    for (int r = 0; r < ROWS; ++r) {
        float wo = 0.f;
        #pragma unroll
        for (int w = 0; w < 4; ++w) if (w < wave) wo += sred[r][w];
        woff[r] = wo;
        const float totY  = sred[r][0] + sred[r][1] + sred[r][2] + sred[r][3];
        const float totY2 = sred[r][4] + sred[r][5] + sred[r][6] + sred[r][7];
        mean[r] = totY * (1.f / (float)L);
        const float var = (totY2 - totY * mean[r]) * (1.f / (float)(L - 1));
        const float s   = fsqrt(var) + EPS;   // std + eps
        epsS[r] = EPS * s;                    // r = u / (sqrt(MV(u^2)) + eps*s)
    }

    // ---- 3. exclusive raw-y prefix -> sp ----
    #pragma unroll
    for (int r = 0; r < ROWS; ++r) {
        if (active) {
            float run = woff[r] + iy[r] - cy[r];
            #pragma unroll
            for (int j = 0; j < CH; ++j) { sp[r][base + j] = run; run += y[r][j]; }
            if (tid == NCHUNK - 1) sp[r][L] = run;
        }
    }
    __syncthreads();                          // B3: y-prefix ready

    // ---- 4. pass B: u = y - MA_sum(y)/251 (z-norm cancels in interior) ----
    const float inv251 = 1.f / 251.f;
    float cu[ROWS], iu[ROWS];
    #pragma unroll
    for (int r = 0; r < ROWS; ++r) {
        float c = 0.f;
        if (active) {
            if (tid >= 9 && tid <= 240) {     // untruncated windows, no mean
                #pragma unroll
                for (int j = 0; j < CH; ++j) {
                    const int i = base + j;
                    const float sumY = sp[r][i + 126] - sp[r][i - 125];
                    const float u = fmaf(sumY, -inv251, y[r][j]);
                    y[r][j] = u;
                    c = fmaf(u, u, c);
                }
            } else {                          // clamped: mean correction
                #pragma unroll
                for (int j = 0; j < CH; ++j) {
                    const int i  = base + j;
                    const int lo = (i > 125) ? i - 125 : 0;
                    const int hi = (i + 126 < L) ? i + 126 : L;
                    const float sumY = sp[r][hi] - sp[r][lo];
                    const float cnt  = (float)(hi - lo);
                    float u = y[r][j] - mean[r] * (1.f - cnt * inv251);
                    u = fmaf(sumY, -inv251, u);
                    y[r][j] = u;
                    c = fmaf(u, u, c);
                }
            }
        }
        float i1 = c;
        #pragma unroll
        for (int d = 1; d < 64; d <<= 1) {
            const float u = __shfl_up(i1, (unsigned)d, 64);
            if (lane >= d) i1 += u;
        }
        if (lane == 63) sred[r][wave] = i1;   // safe: sred reads ended before B3
        cu[r] = c; iu[r] = i1;
    }
    __syncthreads();                          // B4: window reads done, sred(B) ready

    // ---- 5. exclusive u^2-prefix -> sp ----
    #pragma unroll
    for (int r = 0; r < ROWS; ++r) {
        if (active) {
            float wo = 0.f;
            #pragma unroll
            for (int w = 0; w < 4; ++w) if (w < wave) wo += sred[r][w];
            float run = wo + iu[r] - cu[r];
            #pragma unroll
            for (int j = 0; j < CH; ++j) {
                sp[r][base + j] = run;
                run = fmaf(y[r][j], y[r][j], run);
            }
            if (tid == NCHUNK - 1) sp[r][L] = run;
        }
    }
    __syncthreads();                          // B5: u^2-prefix ready

    // ---- 6. epilogue: r = u * t * (1 - epsS*t), t = rsqrt(W) ----
    const float inv501 = 1.f / 501.f;
    #pragma unroll
    for (int r = 0; r < ROWS; ++r) {
        if (active) {
            if (tid >= 17 && tid <= 232) {    // untruncated MV windows
                #pragma unroll
                for (int j = 0; j < CH; ++j) {
                    const int i = base + j;
                    const float W = fmaxf((sp[r][i + 251] - sp[r][i - 250]) * inv501, 0.f);
                    const float t = frsq(W);
                    y[r][j] = y[r][j] * t * fmaf(-epsS[r], t, 1.f);
                }
            } else {                          // clamped
                #pragma unroll
                for (int j = 0; j < CH; ++j) {
                    const int i  = base + j;
                    const int lo = (i > 250) ? i - 250 : 0;
                    const int hi = (i + 251 < L) ? i + 251 : L;
                    const float W = fmaxf((sp[r][hi] - sp[r][lo]) * inv501, 0.f);
                    const float t = frsq(W);
                    y[r][j] = y[r][j] * t * fmaf(-epsS[r], t, 1.f);
                }
            }
        }
    }
    __syncthreads();                          // B6: all prefix reads done

    // ---- 7. bounce r through sp (chunk layout == linear) ----
    #pragma unroll
    for (int r = 0; r < ROWS; ++r) {
        if (active) {
            #pragma unroll
            for (int j = 0; j < CH; ++j) sp[r][base + j] = y[r][j];
        }
    }
    __syncthreads();                          // B7: results staged

    // ---- 8. coalesced store both rows (all LDS reads, then global stores) ----
    {
        float2 v[ROWS][NFULL + 1];
        #pragma unroll
        for (int r = 0; r < ROWS; ++r) {
            const float2* sp2 = reinterpret_cast<const float2*>(&sp[r][0]);
            #pragma unroll
            for (int k = 0; k < NFULL; ++k) v[r][k] = sp2[k * BLK + tid];
            if (tl) v[r][NFULL] = sp2[NFULL * BLK + tid];
        }
        #pragma unroll
        for (int r = 0; r < ROWS; ++r) {
            float2* rout2 = reinterpret_cast<float2*>(out + (row0 + r) * L);
            #pragma unroll
            for (int k = 0; k < NFULL; ++k) rout2[k * BLK + tid] = v[r][k];
            if (tl) rout2[NFULL * BLK + tid] = v[r][NFULL];
        }
    }
}

}  // namespace

extern "C" void kernel_launch(void* const* d_in, const int* in_sizes, int n_in,
                              void* d_out, int out_size, void* d_ws, size_t ws_size,
                              hipStream_t stream) {
    const float* x = (const float*)d_in[0];
    float* out = (float*)d_out;
    const int rows = in_sizes[0] / L;   // 8192
    preproc_kernel<<<rows / ROWS, BLK, 0, stream>>>(x, out);
}

// Round 12
// 44.429 us; speedup vs baseline: 1.1147x; 1.1147x over previous
//
#include <hip/hip_runtime.h>
#include <math.h>

namespace {

constexpr int L      = 3750;
constexpr int NPAIR  = L / 2;     // 1875 float2 per row
constexpr int BLK    = 256;
constexpr int CH     = 15;        // chunk per thread (odd stride => conflict-free)
constexpr int NCHUNK = L / CH;    // 250 active chunk threads
constexpr int NFULL  = NPAIR / BLK;          // 7 full I/O rounds
constexpr int NTAIL  = NPAIR - NFULL * BLK;  // 83
constexpr float EPS  = 1e-5f;

__device__ __forceinline__ float frcp(float x)  { return __builtin_amdgcn_rcpf(x); }
__device__ __forceinline__ float fsqrt(float x) { return __builtin_amdgcn_sqrtf(x); }
__device__ __forceinline__ float frsq(float x)  { return __builtin_amdgcn_rsqf(x); }

// one DPP-add step of the 64-lane inclusive scan (VALU pipe, no LDS traffic)
template<int CTRL, int RMASK>
__device__ __forceinline__ float dpp_add(float v) {
    const int t = __builtin_amdgcn_update_dpp(0, __float_as_int(v),
                                              CTRL, RMASK, 0xf, true);
    return v + __int_as_float(t);
}

// 64-lane inclusive scan: row_shr 1/2/4/8, then bcast15 (rows 1,3), bcast31 (rows 2,3)
__device__ __forceinline__ float wave_iscan(float v) {
    v = dpp_add<0x111, 0xf>(v);
    v = dpp_add<0x112, 0xf>(v);
    v = dpp_add<0x114, 0xf>(v);
    v = dpp_add<0x118, 0xf>(v);
    v = dpp_add<0x142, 0xa>(v);   // lane15 -> lanes 16-31, lane47 -> lanes 48-63
    v = dpp_add<0x143, 0xc>(v);   // lane31 -> lanes 32-63
    return v;                     // lane 63 holds the wave total
}

__global__ __launch_bounds__(BLK, 8)
void preproc_kernel(const float* __restrict__ in, float* __restrict__ out) {
    // ONE row-sized LDS array, reused: staging -> y-prefix -> u^2-prefix -> result
    __shared__ __align__(16) float sp[L + 2];
    __shared__ float sred[8];     // wave partials: [0:4) sum, [4:8) sumsq

    const int tid  = threadIdx.x;
    const int lane = tid & 63;
    const int wave = tid >> 6;
    const size_t rowoff = (size_t)blockIdx.x * (size_t)L;
    const float* rin  = in  + rowoff;
    float*       rout = out + rowoff;

    const bool active = (tid < NCHUNK);
    const int  base   = tid * CH;
    const bool tl     = (tid < NTAIL);

    // ---- 1. coalesced load (batched: all loads in flight, then LDS writes) ----
    {
        const float2* rin2 = reinterpret_cast<const float2*>(rin);
        float2 v[NFULL + 1];
        #pragma unroll
        for (int k = 0; k < NFULL; ++k) v[k] = rin2[k * BLK + tid];
        if (tl) v[NFULL] = rin2[NFULL * BLK + tid];
        float2* sp2 = reinterpret_cast<float2*>(sp);
        #pragma unroll
        for (int k = 0; k < NFULL; ++k) sp2[k * BLK + tid] = v[k];
        if (tl) sp2[NFULL * BLK + tid] = v[NFULL];
    }
    __syncthreads();                          // B1

    // ---- 2. chunk -> registers; block reduce (sum scan + sumsq total via DPP) ----
    float y[CH];
    float cy = 0.f, cy2 = 0.f;
    if (active) {
        #pragma unroll
        for (int j = 0; j < CH; ++j) {
            const float v = sp[base + j];
            y[j] = v;
            cy  += v;
            cy2  = fmaf(v, v, cy2);
        }
    } else {
        #pragma unroll
        for (int j = 0; j < CH; ++j) y[j] = 0.f;
    }
    const float iy = wave_iscan(cy);
    const float t2 = wave_iscan(cy2);         // lane 63 = wave sumsq total
    if (lane == 63) { sred[wave] = iy; sred[4 + wave] = t2; }
    __syncthreads();                          // B2: sred ready, sp reads done
    float woff = 0.f;
    #pragma unroll
    for (int w = 0; w < 4; ++w) if (w < wave) woff += sred[w];
    const float totY  = sred[0] + sred[1] + sred[2] + sred[3];
    const float totY2 = sred[4] + sred[5] + sred[6] + sred[7];
    const float mean  = totY * (1.f / (float)L);
    const float var   = (totY2 - totY * mean) * (1.f / (float)(L - 1));
    const float s     = fsqrt(var) + EPS;     // std + eps
    const float epsS  = EPS * s;              // r = u / (sqrt(MV(u^2)) + eps*s)

    // ---- 3. exclusive raw-y prefix -> sp ----
    {
        float run = woff + iy - cy;           // exclusive prefix at chunk start
        if (active) {
            #pragma unroll
            for (int j = 0; j < CH; ++j) { sp[base + j] = run; run += y[j]; }
            if (tid == NCHUNK - 1) sp[L] = run;
        }
    }
    __syncthreads();                          // B3: y-prefix ready

    // ---- 4. pass B: u = y - MA_sum(y)/251 (z-norm cancels in interior) ----
    const float inv251 = 1.f / 251.f;
    float cu = 0.f;
    if (active) {
        if (tid >= 9 && tid <= 240) {         // untruncated windows, no mean
            #pragma unroll
            for (int j = 0; j < CH; ++j) {
                const int i = base + j;
                const float sumY = sp[i + 126] - sp[i - 125];
                const float u = fmaf(sumY, -inv251, y[j]);
                y[j] = u;
                cu   = fmaf(u, u, cu);
            }
        } else {                              // clamped: mean correction
            #pragma unroll
            for (int j = 0; j < CH; ++j) {
                const int i  = base + j;
                const int lo = (i > 125) ? i - 125 : 0;
                const int hi = (i + 126 < L) ? i + 126 : L;
                const float sumY = sp[hi] - sp[lo];
                const float cnt  = (float)(hi - lo);
                // u = y - m*(1 - cnt/251) - sumY/251
                float u = y[j] - mean * (1.f - cnt * inv251);
                u = fmaf(sumY, -inv251, u);
                y[j] = u;
                cu   = fmaf(u, u, cu);
            }
        }
    }
    const float iu = wave_iscan(cu);
    if (lane == 63) sred[wave] = iu;          // safe: sred(A) last read before B3
    __syncthreads();                          // B4: window reads done, sred(B) ready
    float woff2 = 0.f;
    #pragma unroll
    for (int w = 0; w < 4; ++w) if (w < wave) woff2 += sred[w];

    // ---- 5. exclusive u^2-prefix -> sp ----
    {
        float run = woff2 + iu - cu;
        if (active) {
            #pragma unroll
            for (int j = 0; j < CH; ++j) { sp[base + j] = run; run = fmaf(y[j], y[j], run); }
            if (tid == NCHUNK - 1) sp[L] = run;
        }
    }
    __syncthreads();                          // B5: u^2-prefix ready

    // ---- 6. epilogue: r = u * t * (1 - epsS*t), t = rsqrt(W)  [1st-order exact] ----
    const float inv501 = 1.f / 501.f;
    if (active) {
        if (tid >= 17 && tid <= 232) {        // untruncated MV windows
            #pragma unroll
            for (int j = 0; j < CH; ++j) {
                const int i = base + j;
                const float W = fmaxf((sp[i + 251] - sp[i - 250]) * inv501, 0.f);
                const float t = frsq(W);
                y[j] = y[j] * t * fmaf(-epsS, t, 1.f);
            }
        } else {                              // clamped
            #pragma unroll
            for (int j = 0; j < CH; ++j) {
                const int i  = base + j;
                const int lo = (i > 250) ? i - 250 : 0;
                const int hi = (i + 251 < L) ? i + 251 : L;
                const float W = fmaxf((sp[hi] - sp[lo]) * inv501, 0.f);
                const float t = frsq(W);
                y[j] = y[j] * t * fmaf(-epsS, t, 1.f);
            }
        }
    }
    __syncthreads();                          // B6: all prefix reads done

    // ---- 7. bounce r through sp (chunk layout == linear) ----
    if (active) {
        #pragma unroll
        for (int j = 0; j < CH; ++j) sp[base + j] = y[j];
    }
    __syncthreads();                          // B7: result staged

    // ---- 8. coalesced store (batched: all LDS reads, then global stores) ----
    {
        const float2* sp2 = reinterpret_cast<const float2*>(sp);
        float2* rout2 = reinterpret_cast<float2*>(rout);
        float2 v[NFULL + 1];
        #pragma unroll
        for (int k = 0; k < NFULL; ++k) v[k] = sp2[k * BLK + tid];
        if (tl) v[NFULL] = sp2[NFULL * BLK + tid];
        #pragma unroll
        for (int k = 0; k < NFULL; ++k) rout2[k * BLK + tid] = v[k];
        if (tl) rout2[NFULL * BLK + tid] = v[NFULL];
    }
}

}  // namespace

extern "C" void kernel_launch(void* const* d_in, const int* in_sizes, int n_in,
                              void* d_out, int out_size, void* d_ws, size_t ws_size,
                              hipStream_t stream) {
    const float* x = (const float*)d_in[0];
    float* out = (float*)d_out;
    const int rows = in_sizes[0] / L;   // 8192
    preproc_kernel<<<rows, BLK, 0, stream>>>(x, out);
}